// Round 1
// baseline (448.772 us; speedup 1.0000x reference)
//
#include <hip/hip_runtime.h>

// GRU: H=31 hidden, B=2048 batches, T=512 timesteps, FC head to 2 outputs.
// One wave64 per batch. h[i] lives in lane i (i<31). Broadcasts via v_readlane
// (SGPR operand of v_fmac), so the recurrence uses no LDS at all.
//
// Lane roles (li = lane&31, half = lane>>5):
//   pass A (h-src, W_hh): low: r-row li      | high: z-row 31+li   -> accA
//   pass C (x-src, W_ih): low: r-row li      | high: z-row 31+li   -> accA
//   pass B (h-src):       low: W_hh n-row    | high lanes 32/33: W_fc rows -> accB
//   pass D (x-src):       low: W_ih n-row    | high: idle          -> accD
// sigmoid(accA) gives r (low) and z (high) in one shot; shfl_xor(32) swaps.

constexpr int BB = 2048;
constexpr int TT = 512;
constexpr int HH = 31;

__device__ __forceinline__ float bcast(float v, int lane) {
    return __int_as_float(__builtin_amdgcn_readlane(__float_as_int(v), lane));
}

__global__ __launch_bounds__(256, 2) void gru_fused_kernel(
    const float* __restrict__ x, const float* __restrict__ W_ih,
    const float* __restrict__ W_hh, const float* __restrict__ b_ih,
    const float* __restrict__ b_hh, const float* __restrict__ W_fc,
    const float* __restrict__ b_fc, float* __restrict__ out)
{
    const int tid  = threadIdx.x;
    const int wave = tid >> 6;
    const int lane = tid & 63;
    const int li   = lane & 31;
    const int half = lane >> 5;
    const int b    = blockIdx.x * 4 + wave;

    const bool unitlane = (li < HH);           // lane owns hidden unit li
    const bool low      = (half == 0);
    const bool fclane   = (!low) && (li < 2);  // lanes 32,33 do the FC head

    // Row indices (always in-bounds even for inactive lanes).
    const int rA  = unitlane ? (half * HH + li) : 0;  // r (low) / z (high) rows
    const int rBD = 2 * HH + (unitlane ? li : 0);     // n rows (low half)
    const int fcr = fclane ? li : 0;

    const float* WhhA = W_hh + rA  * HH;
    const float* WihA = W_ih + rA  * HH;
    const float* WhhB = W_hh + rBD * HH;
    const float* WihD = W_ih + rBD * HH;
    const float* WfcB = W_fc + fcr * HH;

    const float fcmask = fclane ? 1.f : 0.f;

    float wA[HH], wB[HH], wC[HH], wD[HH];
#pragma unroll
    for (int j = 0; j < HH; ++j) {
        float whA = WhhA[j], wiA = WihA[j];
        float whB = WhhB[j], wiD = WihD[j];
        float wfc = WfcB[j];
        wA[j] = unitlane ? whA : 0.f;
        wC[j] = unitlane ? wiA : 0.f;
        wB[j] = low ? whB : wfc * fcmask;
        wD[j] = low ? wiD : 0.f;
    }
    const float biasA = unitlane ? (b_ih[rA] + b_hh[rA]) : 0.f;
    const float biasB = low ? b_hh[rBD] : b_fc[fcr] * fcmask;
    const float biasD = low ? b_ih[rBD] : 0.f;

    const float* xb   = x + (size_t)b * TT * HH;
    float*       outb = out + (size_t)b * TT * 2;

    float hval = 0.f;                                // h[li] in lane li (low half)
    float xv   = (lane < HH) ? xb[lane] : 0.f;       // x[b,0,lane]

    for (int t = 0; t < TT; ++t) {
        // Prefetch x for t+1 (latency hidden under this step's compute).
        float xn = 0.f;
        if (lane < HH && t + 1 < TT) xn = xb[(size_t)(t + 1) * HH + lane];

        // Split accumulators to keep FMA dependency chains short.
        float a0 = biasA, a1 = 0.f;
        float b0 = biasB, b1 = 0.f;
        float d0 = biasD, d1 = 0.f;
#pragma unroll
        for (int j = 0; j < HH; ++j) {
            const float hj = bcast(hval, j);
            const float xj = bcast(xv, j);
            if (j & 1) {
                a1 = fmaf(hj, wA[j], a1);
                a1 = fmaf(xj, wC[j], a1);
                b1 = fmaf(hj, wB[j], b1);
                d1 = fmaf(xj, wD[j], d1);
            } else {
                a0 = fmaf(hj, wA[j], a0);
                a0 = fmaf(xj, wC[j], a0);
                b0 = fmaf(hj, wB[j], b0);
                d0 = fmaf(xj, wD[j], d0);
            }
        }
        const float accA = a0 + a1;   // r-preact (low) | z-preact (high)
        const float accB = b0 + b1;   // h-side n-preact (low) | fc of h_{t-1} (high 32/33)
        const float accD = d0 + d1;   // x-side n-preact (low)

        // FC output for h_{t-1} (lanes 32,33). t=0 would be h_{-1}: skip.
        if (fclane && t >= 1) outb[(size_t)(t - 1) * 2 + li] = accB;

        // Gates. g = sigmoid(accA): r in low lanes, z in high lanes.
        const float e   = __expf(-accA);
        const float g   = __fdividef(1.f, 1.f + e);
        const float zsw = __shfl_xor(g, 32);              // z (low) | r (high)
        const float npre = fmaf(g, accB, accD);           // inn + r*hn   (low)
        const float u   = __expf(-2.f * npre);
        const float n   = __fdividef(2.f, 1.f + u) - 1.f; // tanh(npre)
        const float hnew = n + zsw * (hval - n);          // (1-z)n + z h
        hval = (low && unitlane) ? hnew : hval;
        xv = xn;
    }

    // Final FC for h_{T-1}.
    float accF = biasB;
#pragma unroll
    for (int j = 0; j < HH; ++j) accF = fmaf(bcast(hval, j), wB[j], accF);
    if (fclane) outb[(size_t)(TT - 1) * 2 + li] = accF;
}

extern "C" void kernel_launch(void* const* d_in, const int* in_sizes, int n_in,
                              void* d_out, int out_size, void* d_ws, size_t ws_size,
                              hipStream_t stream) {
    const float* x    = (const float*)d_in[0];
    const float* W_ih = (const float*)d_in[1];
    const float* W_hh = (const float*)d_in[2];
    const float* b_ih = (const float*)d_in[3];
    const float* b_hh = (const float*)d_in[4];
    const float* W_fc = (const float*)d_in[5];
    const float* b_fc = (const float*)d_in[6];
    float* out = (float*)d_out;

    dim3 grid(BB / 4);   // 512 blocks x 4 waves = 2048 waves, 1 batch/wave
    dim3 block(256);
    gru_fused_kernel<<<grid, block, 0, stream>>>(x, W_ih, W_hh, b_ih, b_hh,
                                                 W_fc, b_fc, out);
}

// Round 2
// 345.287 us; speedup vs baseline: 1.2997x; 1.2997x over previous
//
#include <hip/hip_runtime.h>

// GRU H=31, B=2048, T=512, FC->2. One wave64 per batch.
// f16-pair dot2 formulation: weights held as packed half2 in VGPRs (64 regs),
// h_{t-1} and x_t broadcast as packed f16 pairs via v_readlane (16+16/step),
// dots via v_dot2_f32_f16 (f32 accumulate).
//
// Lane (li=lane&31, half=lane>>5) row assignment:
//   slot A (acc aH+aX): li<31: r-row (low) / z-row (high) of W_hh (h-stream)
//                       and W_ih (x-stream). lane(31,low): FC row 1 in h-stream.
//   slot B (acc bH+bX): li<31 low: n-row of W_hh (h-stream, x-stream zeroed)
//                       li<31 high: n-row of W_ih (x-stream, h-stream zeroed)
//                       lane(31,low): FC row 0 in h-stream.
// n-combine and z via one __shfl_xor(32) each. FC of h_{t-1} falls out of
// lane 31's accumulators during step t; epilogue handles t=T-1.

constexpr int BB = 2048;
constexpr int TT = 512;
constexpr int HH = 31;

typedef _Float16 h2 __attribute__((ext_vector_type(2)));

__device__ __forceinline__ float dot2p(int pks, h2 w, float acc) {
#if __has_builtin(__builtin_amdgcn_fdot2)
    return __builtin_amdgcn_fdot2(__builtin_bit_cast(h2, pks), w, acc, false);
#else
    h2 a = __builtin_bit_cast(h2, pks);
    return acc + (float)a.x * (float)w.x + (float)a.y * (float)w.y;
#endif
}

__global__ __launch_bounds__(256, 2) void gru_f16_kernel(
    const float* __restrict__ x, const float* __restrict__ W_ih,
    const float* __restrict__ W_hh, const float* __restrict__ b_ih,
    const float* __restrict__ b_hh, const float* __restrict__ W_fc,
    const float* __restrict__ b_fc, float* __restrict__ out)
{
    const int tid  = threadIdx.x;
    const int wave = tid >> 6;
    const int lane = tid & 63;
    const int li   = lane & 31;
    const int half = lane >> 5;
    const int b    = blockIdx.x * 4 + wave;

    const bool low  = (half == 0);
    const bool unit = (li < HH);

    // Weight row pointers per lane (nullptr -> zero weights).
    const float *pAh = nullptr, *pAx = nullptr, *pBh = nullptr, *pBx = nullptr;
    if (unit) {
        pAh = W_hh + (half * HH + li) * HH;
        pAx = W_ih + (half * HH + li) * HH;
        if (low) pBh = W_hh + (2 * HH + li) * HH;
        else     pBx = W_ih + (2 * HH + li) * HH;
    } else if (low) {            // lane 31: FC head
        pAh = W_fc + HH;         // FC row 1
        pBh = W_fc;              // FC row 0
    }

    // Pack rows to half2 pairs (K=31 padded to 32; RTN via C cast).
    h2 wAh[16], wAx[16], wBh[16], wBx[16];
#pragma unroll
    for (int m = 0; m < 16; ++m) {
        auto pk = [&](const float* p) -> h2 {
            float lo = p ? p[2 * m] : 0.f;
            float hi = (p && (2 * m + 1) < HH) ? p[2 * m + 1] : 0.f;
            h2 r; r.x = (_Float16)lo; r.y = (_Float16)hi; return r;
        };
        wAh[m] = pk(pAh); wAx[m] = pk(pAx); wBh[m] = pk(pBh); wBx[m] = pk(pBx);
    }

    float accA0 = 0.f, accB0 = 0.f;
    if (unit) {
        const int rA = half * HH + li;
        accA0 = b_ih[rA] + b_hh[rA];
        accB0 = low ? b_hh[2 * HH + li] : b_ih[2 * HH + li];
    } else if (low) {
        accA0 = b_fc[1]; accB0 = b_fc[0];
    }

    const float* xb   = x + (size_t)b * TT * HH;
    float*       outb = out + (size_t)b * TT * 2;

    float hval = 0.f;                            // h[li] in low lane li
    float xv   = (lane < HH) ? xb[lane] : 0.f;   // x[b,0,lane]

    for (int t = 0; t < TT; ++t) {
        float xn = 0.f;
        if (lane < HH && t + 1 < TT) xn = xb[(size_t)(t + 1) * HH + lane];

        // Pack h_{t-1}, x_t into f16 pairs on even low lanes:
        // pair m = {v_2m, v_2m+1} lives in lane 2m.
        const int ho  = __builtin_bit_cast(int, __builtin_amdgcn_cvt_pkrtz(hval, hval));
        const int xo  = __builtin_bit_cast(int, __builtin_amdgcn_cvt_pkrtz(xv, xv));
        const int hp_ = __shfl_xor(ho, 1);
        const int xp_ = __shfl_xor(xo, 1);
        const int hpk = __builtin_amdgcn_perm(hp_, ho, 0x05040100);
        const int xpk = __builtin_amdgcn_perm(xp_, xo, 0x05040100);

        float aH = accA0, aX = 0.f, bH = accB0, bX = 0.f;
#pragma unroll
        for (int m = 0; m < 16; ++m) {
            const int hs = __builtin_amdgcn_readlane(hpk, 2 * m);
            const int xs = __builtin_amdgcn_readlane(xpk, 2 * m);
            aH = dot2p(hs, wAh[m], aH);
            aX = dot2p(xs, wAx[m], aX);
            bH = dot2p(hs, wBh[m], bH);
            bX = dot2p(xs, wBx[m], bX);
        }
        const float accA = aH + aX;   // r|z pre-act (li<31); FC1 in lane 31
        const float accB = bH + bX;   // hn (low) | inn (high); FC0 in lane 31
        const float fc1 = accA, fc0 = accB;

        // Gates.
        const float e   = __expf(-accA);
        const float g   = __fdividef(1.f, 1.f + e);     // r (low) | z (high)
        const float zsw = __shfl_xor(g, 32);            // z to low half
        const float inn = __shfl_xor(accB, 32);         // x-side n pre-act to low
        const float npre = fmaf(g, accB, inn);          // inn + r*hn
        const float u   = __expf(-2.f * npre);
        const float nn  = __fdividef(2.f, 1.f + u) - 1.f;
        const float hnew = nn + zsw * (hval - nn);

        if (lane == 31 && t > 0)
            *(float2*)(outb + (size_t)(t - 1) * 2) = make_float2(fc0, fc1);

        hval = (low && unit) ? hnew : hval;
        xv = xn;
    }

    // Epilogue: FC of h_{T-1}.
    {
        const int ho  = __builtin_bit_cast(int, __builtin_amdgcn_cvt_pkrtz(hval, hval));
        const int hp_ = __shfl_xor(ho, 1);
        const int hpk = __builtin_amdgcn_perm(hp_, ho, 0x05040100);
        float fA = accA0, fB = accB0;
#pragma unroll
        for (int m = 0; m < 16; ++m) {
            const int hs = __builtin_amdgcn_readlane(hpk, 2 * m);
            fA = dot2p(hs, wAh[m], fA);
            fB = dot2p(hs, wBh[m], fB);
        }
        if (lane == 31)
            *(float2*)(outb + (size_t)(TT - 1) * 2) = make_float2(fB, fA);
    }
}

extern "C" void kernel_launch(void* const* d_in, const int* in_sizes, int n_in,
                              void* d_out, int out_size, void* d_ws, size_t ws_size,
                              hipStream_t stream) {
    const float* x    = (const float*)d_in[0];
    const float* W_ih = (const float*)d_in[1];
    const float* W_hh = (const float*)d_in[2];
    const float* b_ih = (const float*)d_in[3];
    const float* b_hh = (const float*)d_in[4];
    const float* W_fc = (const float*)d_in[5];
    const float* b_fc = (const float*)d_in[6];
    float* out = (float*)d_out;

    dim3 grid(BB / 4);   // 512 blocks x 4 waves = 2048 waves, 1 batch/wave
    dim3 block(256);
    gru_f16_kernel<<<grid, block, 0, stream>>>(x, W_ih, W_hh, b_ih, b_hh,
                                               W_fc, b_fc, out);
}

// Round 3
// 283.873 us; speedup vs baseline: 1.5809x; 1.2163x over previous
//
#include <hip/hip_runtime.h>

// GRU H=31, B=2048, T=512, FC->2.
// 2 batches per wave64 (half = lane>>5 selects batch). Lane li<31 owns hidden
// unit li of its half's batch: rows r=li, z=31+li, n=62+li of both W_hh and
// W_ih as 6 packed-f16 dot2 streams. Gates fully lane-local (no cross-lane).
// Lane li==31 computes the FC head (rows W_fc[0],W_fc[1]) on the h-streams.
// Broadcast of h_{t-1} and x_t via LDS: f16 scalars written per-lane
// (ds_write_b16), read back as 4x ds_read_b128 per vector (same-address
// broadcast, halves on disjoint banks). x double-buffered + register
// prefetch; next-step x pre-read into regs so only the h write->read
// turnaround is on the serial path. 1024 waves = 1 wave/SIMD.

constexpr int BB = 2048, TT = 512, HH = 31;

typedef _Float16 hf2 __attribute__((ext_vector_type(2)));

__device__ __forceinline__ float dot2(int pk, hf2 w, float acc) {
#if __has_builtin(__builtin_amdgcn_fdot2)
    return __builtin_amdgcn_fdot2(__builtin_bit_cast(hf2, pk), w, acc, false);
#else
    hf2 a = __builtin_bit_cast(hf2, pk);
    return acc + (float)a.x * (float)w.x + (float)a.y * (float)w.y;
#endif
}

__global__ __launch_bounds__(64, 1) void gru_pair_kernel(
    const float* __restrict__ x, const float* __restrict__ W_ih,
    const float* __restrict__ W_hh, const float* __restrict__ b_ih,
    const float* __restrict__ b_hh, const float* __restrict__ W_fc,
    const float* __restrict__ b_fc, float* __restrict__ out)
{
    __shared__ _Float16 hbuf[2][32];        // [half][unit]
    __shared__ _Float16 xbuf[2][2][32];     // [slot][half][elem]

    const int lane = threadIdx.x & 63;
    const int li   = lane & 31;
    const int half = lane >> 5;
    const int b    = blockIdx.x * 2 + half;
    const bool unit = (li < HH);

    // Row pointers (nullptr -> zero weights). Lane 31: FC rows on h-streams.
    const float* ph0 = unit ? W_hh + (size_t)li * HH            : W_fc;
    const float* ph1 = unit ? W_hh + (size_t)(HH + li) * HH     : W_fc + HH;
    const float* ph2 = unit ? W_hh + (size_t)(2 * HH + li) * HH : nullptr;
    const float* px0 = unit ? W_ih + (size_t)li * HH            : nullptr;
    const float* px1 = unit ? W_ih + (size_t)(HH + li) * HH     : nullptr;
    const float* px2 = unit ? W_ih + (size_t)(2 * HH + li) * HH : nullptr;

    hf2 wh0[16], wh1[16], wh2[16], wx0[16], wx1[16], wx2[16];
#pragma unroll
    for (int m = 0; m < 16; ++m) {
        auto pk = [&](const float* p) -> hf2 {
            hf2 r;
            r.x = p ? (_Float16)p[2 * m] : (_Float16)0.f;
            r.y = (p && (2 * m + 1) < HH) ? (_Float16)p[2 * m + 1] : (_Float16)0.f;
            return r;
        };
        wh0[m] = pk(ph0); wh1[m] = pk(ph1); wh2[m] = pk(ph2);
        wx0[m] = pk(px0); wx1[m] = pk(px1); wx2[m] = pk(px2);
    }

    float arH0, azH0, anH0, anX0;
    if (unit) {
        arH0 = b_ih[li] + b_hh[li];
        azH0 = b_ih[HH + li] + b_hh[HH + li];
        anH0 = b_hh[2 * HH + li];
        anX0 = b_ih[2 * HH + li];
    } else {
        arH0 = b_fc[0]; azH0 = b_fc[1]; anH0 = 0.f; anX0 = 0.f;
    }

    const float* xb   = x + (size_t)b * TT * HH;
    float*       outb = out + (size_t)b * TT * 2;

    // LDS init: h_0 = 0 (incl pad), x_0 -> slot0, x_1 -> slot1 (pads zeroed).
    hbuf[half][li]    = (_Float16)0.f;
    xbuf[0][half][li] = unit ? (_Float16)xb[li]      : (_Float16)0.f;
    xbuf[1][half][li] = unit ? (_Float16)xb[HH + li] : (_Float16)0.f;
    float xpre = unit ? xb[(size_t)2 * HH + li] : 0.f;   // x_2 in flight
    float hval = 0.f;

    const int4* HP  = (const int4*)(&hbuf[half][0]);
    const int4* XB0 = (const int4*)(&xbuf[0][half][0]);
    const int4* XB1 = (const int4*)(&xbuf[1][half][0]);

    // x_0 pre-read into registers.
    int4 xq0 = XB0[0], xq1 = XB0[1], xq2 = XB0[2], xq3 = XB0[3];

#pragma unroll 2
    for (int t = 0; t < TT; ++t) {
        int4 hq0 = HP[0], hq1 = HP[1], hq2 = HP[2], hq3 = HP[3];

        float arH = arH0, azH = azH0, anH = anH0;
        float arX = 0.f, azX = 0.f, anX = anX0;
#define STEPM(m, hp, xp) \
        arH = dot2(hp, wh0[m], arH); azH = dot2(hp, wh1[m], azH); \
        anH = dot2(hp, wh2[m], anH); arX = dot2(xp, wx0[m], arX); \
        azX = dot2(xp, wx1[m], azX); anX = dot2(xp, wx2[m], anX);
        STEPM(0,  hq0.x, xq0.x) STEPM(1,  hq0.y, xq0.y)
        STEPM(2,  hq0.z, xq0.z) STEPM(3,  hq0.w, xq0.w)
        STEPM(4,  hq1.x, xq1.x) STEPM(5,  hq1.y, xq1.y)
        STEPM(6,  hq1.z, xq1.z) STEPM(7,  hq1.w, xq1.w)
        STEPM(8,  hq2.x, xq2.x) STEPM(9,  hq2.y, xq2.y)
        STEPM(10, hq2.z, xq2.z) STEPM(11, hq2.w, xq2.w)
        STEPM(12, hq3.x, xq3.x) STEPM(13, hq3.y, xq3.y)
        STEPM(14, hq3.z, xq3.z) STEPM(15, hq3.w, xq3.w)
#undef STEPM

        const float sumr = arH + arX;   // r pre-act | lane31: FC0(h_{t-1})
        const float sumz = azH + azX;   // z pre-act | lane31: FC1(h_{t-1})
        if (li == 31 && t > 0)
            *(float2*)(outb + (size_t)(t - 1) * 2) = make_float2(sumr, sumz);

        const float r    = __fdividef(1.f, 1.f + __expf(-sumr));
        const float z    = __fdividef(1.f, 1.f + __expf(-sumz));
        const float npre = fmaf(r, anH, anX);
        const float nn   = __fdividef(2.f, 1.f + __expf(-2.f * npre)) - 1.f;
        const float hnew = nn + z * (hval - nn);
        hval = unit ? hnew : 0.f;                 // lane31 stays 0 (pad)
        hbuf[half][li] = (_Float16)hval;

        // Stage x_{t+2} into the slot just freed (t&1); its reads happened
        // at the bottom of iteration t-2 (in-order DS => safe).
        xbuf[t & 1][half][li] = unit ? (_Float16)xpre : (_Float16)0.f;
        int tn = t + 3; if (tn > TT - 1) tn = TT - 1;
        xpre = unit ? xb[(size_t)tn * HH + li] : 0.f;

        // Pre-read next step's x (slot (t+1)&1) into registers.
        const int4* XN = (t & 1) ? XB0 : XB1;
        xq0 = XN[0]; xq1 = XN[1]; xq2 = XN[2]; xq3 = XN[3];
    }

    // Epilogue: FC(h_{TT-1}).
    {
        int4 hq0 = HP[0], hq1 = HP[1], hq2 = HP[2], hq3 = HP[3];
        float f0 = arH0, f1 = azH0;
#define FST(m, hp) f0 = dot2(hp, wh0[m], f0); f1 = dot2(hp, wh1[m], f1);
        FST(0,  hq0.x) FST(1,  hq0.y) FST(2,  hq0.z) FST(3,  hq0.w)
        FST(4,  hq1.x) FST(5,  hq1.y) FST(6,  hq1.z) FST(7,  hq1.w)
        FST(8,  hq2.x) FST(9,  hq2.y) FST(10, hq2.z) FST(11, hq2.w)
        FST(12, hq3.x) FST(13, hq3.y) FST(14, hq3.z) FST(15, hq3.w)
#undef FST
        if (li == 31)
            *(float2*)(outb + (size_t)(TT - 1) * 2) = make_float2(f0, f1);
    }
}

extern "C" void kernel_launch(void* const* d_in, const int* in_sizes, int n_in,
                              void* d_out, int out_size, void* d_ws, size_t ws_size,
                              hipStream_t stream) {
    const float* x    = (const float*)d_in[0];
    const float* W_ih = (const float*)d_in[1];
    const float* W_hh = (const float*)d_in[2];
    const float* b_ih = (const float*)d_in[3];
    const float* b_hh = (const float*)d_in[4];
    const float* W_fc = (const float*)d_in[5];
    const float* b_fc = (const float*)d_in[6];
    float* out = (float*)d_out;

    dim3 grid(BB / 2);   // 1024 blocks x 1 wave, 2 batches per wave
    dim3 block(64);
    gru_pair_kernel<<<grid, block, 0, stream>>>(x, W_ih, W_hh, b_ih, b_hh,
                                                W_fc, b_fc, out);
}